// Round 7
// baseline (757.108 us; speedup 1.0000x reference)
//
#include <hip/hip_runtime.h>
#include <math.h>

#define BB 4
#define NN 32768
#define CC 512
#define MM 512
#define CAP 8192
#define TPB 512
#define KPT (CAP / TPB)    // 16 slots per thread
#define NPAIR (KPT / 2)

typedef float f32x2 __attribute__((ext_vector_type(2)));
typedef unsigned long long u64;

// ---- workspace layout (bytes) ----
#define OFF_G      0
#define OFF_MASK   (OFF_G + BB*NN*4)           // graspness f32
#define OFF_CNT    (OFF_MASK + BB*NN)          // mask u8
#define OFF_CIDX   (OFF_CNT + 256)             // cnt ints (padded)
#define OFF_CXYZD  (OFF_CIDX + BB*CAP*4)       // compacted orig indices
#define OFF_IDXSEL (OFF_CXYZD + BB*CAP*16)     // compacted float4 {x,y,z, idx_bits}
#define OFF_DSLOW  (OFF_IDXSEL + BB*MM*4)      // slow-path dist array
// total = OFF_DSLOW + BB*NN*4 ~= 1.85 MB

// ---------------- kernel 1: scoring heads + mask (float4-vectorized) ----------------
__global__ __launch_bounds__(256) void k_score(const float* __restrict__ feat,
                                               const float* __restrict__ Wobj,
                                               const float* __restrict__ bobj,
                                               const float* __restrict__ Wg,
                                               const float* __restrict__ bg,
                                               float* __restrict__ g_out,
                                               unsigned char* __restrict__ mask_out) {
    __shared__ float w0[CC], w1[CC], wg[CC];
    for (int c = threadIdx.x; c < CC; c += 256) {
        w0[c] = Wobj[c];
        w1[c] = Wobj[CC + c];
        wg[c] = Wg[c];
    }
    __syncthreads();
    int b = blockIdx.y;
    int n0 = (blockIdx.x * 256 + threadIdx.x) * 4;
    const float* f = feat + (size_t)b * CC * NN + n0;
    double a0[4] = {0,0,0,0}, a1[4] = {0,0,0,0}, ag[4] = {0,0,0,0};
#pragma unroll 8
    for (int c = 0; c < CC; c++) {
        float4 v = *(const float4*)(f + (size_t)c * NN);
        double wa = (double)w0[c], wb = (double)w1[c], wc = (double)wg[c];
        a0[0] += (double)v.x * wa; a0[1] += (double)v.y * wa;
        a0[2] += (double)v.z * wa; a0[3] += (double)v.w * wa;
        a1[0] += (double)v.x * wb; a1[1] += (double)v.y * wb;
        a1[2] += (double)v.z * wb; a1[3] += (double)v.w * wb;
        ag[0] += (double)v.x * wc; ag[1] += (double)v.y * wc;
        ag[2] += (double)v.z * wc; ag[3] += (double)v.w * wc;
    }
    double db0 = (double)bobj[0], db1 = (double)bobj[1], dbg = (double)bg[0];
    float4 gv;
    uchar4 mk;
    {
        float o0, o1, g;
        o0 = (float)(a0[0] + db0); o1 = (float)(a1[0] + db1); g = (float)(ag[0] + dbg);
        gv.x = g; mk.x = (o1 > o0 && g > 0.1f) ? 1 : 0;
        o0 = (float)(a0[1] + db0); o1 = (float)(a1[1] + db1); g = (float)(ag[1] + dbg);
        gv.y = g; mk.y = (o1 > o0 && g > 0.1f) ? 1 : 0;
        o0 = (float)(a0[2] + db0); o1 = (float)(a1[2] + db1); g = (float)(ag[2] + dbg);
        gv.z = g; mk.z = (o1 > o0 && g > 0.1f) ? 1 : 0;
        o0 = (float)(a0[3] + db0); o1 = (float)(a1[3] + db1); g = (float)(ag[3] + dbg);
        gv.w = g; mk.w = (o1 > o0 && g > 0.1f) ? 1 : 0;
    }
    *(float4*)(g_out + b * NN + n0) = gv;
    *(uchar4*)(mask_out + b * NN + n0) = mk;
}

// ---------------- kernel 2: stable compaction of masked points ----------------
__global__ __launch_bounds__(1024) void k_compact(const float* __restrict__ pc,
                                                  const unsigned char* __restrict__ mask,
                                                  int* __restrict__ cnt,
                                                  int* __restrict__ cidx,
                                                  float4* __restrict__ cxyzd) {
    int b = blockIdx.x, tid = threadIdx.x;
    int lane = tid & 63, wv = tid >> 6;
    __shared__ int wcnt[16], woff[16];
    __shared__ int base;
    if (tid == 0) base = 0;
    __syncthreads();
    for (int ch = 0; ch < NN / 1024; ch++) {
        int n = ch * 1024 + tid;
        bool m = mask[(size_t)b * NN + n] != 0;
        unsigned long long bal = __ballot(m);
        int before = __popcll(bal & ((1ull << lane) - 1ull));
        if (lane == 0) wcnt[wv] = __popcll(bal);
        __syncthreads();
        if (tid == 0) {
            int r = base;
            for (int w = 0; w < 16; w++) { woff[w] = r; r += wcnt[w]; }
            base = r;
        }
        __syncthreads();
        if (m) {
            int pos = woff[wv] + before;
            if (pos < CAP) {
                cidx[b * CAP + pos] = n;
                const float* p = pc + ((size_t)b * NN + n) * 3;
                cxyzd[b * CAP + pos] = make_float4(p[0], p[1], p[2], __int_as_float(n));
            }
        }
        __syncthreads();
    }
    if (tid == 0) cnt[b] = base;
}

// ---- DPP f32 max step: builtin form (compiler inserts VALU->DPP hazard nops) ----
template<int CTRL, int RMASK>
__device__ __forceinline__ float dpp_fmax(float v) {
    int o = __builtin_amdgcn_update_dpp(__float_as_int(v), __float_as_int(v),
                                        CTRL, RMASK, 0xF, false);
    return fmaxf(v, __int_as_float(o));
}

// ---------------- kernel 3: FPS — value-first 2-phase argmax, coords in key payload ----
__global__ __launch_bounds__(TPB, 1) void k_fps(const int* __restrict__ cnt,
                                                const float4* __restrict__ cxyzd_g,
                                                int* __restrict__ idxsel) {
    int b = blockIdx.x, tid = threadIdx.x;
    int nc = cnt[b];
    if (nc == 0) {  // no graspable points: reference selects index 0 forever
        for (int i = tid; i < MM; i += TPB) idxsel[b * MM + i] = 0;
        return;
    }
    if (nc > CAP) return;  // slow-path kernel handles this

    __shared__ float4 redv4[2];            // 8 per-wave value winners
    __shared__ u64 slots[2][4];            // rotating {p<<32 | bits(x/y/z/origidx)}

    f32x2 px2[NPAIR], py2[NPAIR], pz2[NPAIR], pw2[NPAIR];
    float pd[KPT];
    const float4* src = cxyzd_g + (size_t)b * CAP;
#pragma unroll
    for (int j = 0; j < NPAIR; j++) {
        int p0 = (2 * j) * TPB + tid;
        int p1 = (2 * j + 1) * TPB + tid;
        bool v0 = p0 < nc, v1 = p1 < nc;
        float4 a = v0 ? src[p0] : make_float4(0.f, 0.f, 0.f, 0.f);
        float4 c = v1 ? src[p1] : make_float4(0.f, 0.f, 0.f, 0.f);
        px2[j] = (f32x2){a.x, c.x};
        py2[j] = (f32x2){a.y, c.y};
        pz2[j] = (f32x2){a.z, c.z};
        pw2[j] = (f32x2){a.w, c.w};
        pd[2 * j]     = v0 ? __builtin_inff() : -__builtin_inff();
        pd[2 * j + 1] = v1 ? __builtin_inff() : -__builtin_inff();
    }
    if (tid == 0) {   // first center = compacted point 0 (owned by tid 0, slot 0, half .x)
        slots[0][0] = (u64)(unsigned)__float_as_int(px2[0].x);
        slots[0][1] = (u64)(unsigned)__float_as_int(py2[0].x);
        slots[0][2] = (u64)(unsigned)__float_as_int(pz2[0].x);
        slots[0][3] = (u64)(unsigned)__float_as_int(pw2[0].x);
    }
    __syncthreads();

    int cur = 0;
    for (int it = 0; it < MM; it++) {
        u64 q0 = slots[cur][0];
        u64 q1 = slots[cur][1];
        u64 q2 = slots[cur][2];
        u64 q3 = slots[cur][3];
        float cx = __int_as_float((int)(unsigned)q0);
        float cy = __int_as_float((int)(unsigned)q1);
        float cz = __int_as_float((int)(unsigned)q2);
        if (tid == 0) {
            idxsel[b * MM + it] = (int)(unsigned)q3;   // emit current center's orig idx
            slots[cur ^ 1][0] = ~0ull;                 // init next-slot (writers act after barA)
            slots[cur ^ 1][1] = ~0ull;
            slots[cur ^ 1][2] = ~0ull;
            slots[cur ^ 1][3] = ~0ull;
        }
        f32x2 ncx = {-cx, -cx};
        f32x2 ncy = {-cy, -cy};
        f32x2 ncz = {-cz, -cz};

        float bmax = -__builtin_inff();
#pragma unroll
        for (int j = 0; j < NPAIR; j++) {
            f32x2 d2, t;
            // exact f32 per half, no contraction: ((dx*dx + dy*dy) + dz*dz)
            asm("v_pk_add_f32 %0, %2, %4\n\t"
                "v_pk_add_f32 %1, %3, %5\n\t"
                "v_pk_mul_f32 %0, %0, %0\n\t"
                "v_pk_mul_f32 %1, %1, %1\n\t"
                "v_pk_add_f32 %0, %0, %1\n\t"
                "v_pk_add_f32 %1, %6, %7\n\t"
                "v_pk_mul_f32 %1, %1, %1\n\t"
                "v_pk_add_f32 %0, %0, %1"
                : "=&v"(d2), "=&v"(t)
                : "v"(px2[j]), "v"(py2[j]), "v"(ncx), "v"(ncy), "v"(pz2[j]), "v"(ncz));
            float nd0 = fminf(pd[2 * j], d2.x);
            float nd1 = fminf(pd[2 * j + 1], d2.y);
            pd[2 * j] = nd0;
            pd[2 * j + 1] = nd1;
            // running max via single v_max3 (exact; value domain has no NaN/-0)
            asm("v_max3_f32 %0, %1, %2, %3" : "=v"(bmax) : "v"(nd0), "v"(nd1), "v"(bmax));
        }

        // 64-lane value max via DPP builtins (hazard-safe): lane 63 ends with wave max
        float wmax = bmax;
        wmax = dpp_fmax<0x111, 0xF>(wmax);  // row_shr:1
        wmax = dpp_fmax<0x112, 0xF>(wmax);  // row_shr:2
        wmax = dpp_fmax<0x114, 0xF>(wmax);  // row_shr:4
        wmax = dpp_fmax<0x118, 0xF>(wmax);  // row_shr:8
        wmax = dpp_fmax<0x142, 0xA>(wmax);  // row_bcast:15 -> rows 1,3
        wmax = dpp_fmax<0x143, 0xC>(wmax);  // row_bcast:31 -> rows 2,3
        if ((tid & 63) == 63) ((float*)redv4)[tid >> 6] = wmax;
        __syncthreads();   // barrier A: all wave winners published

        float4 ra = redv4[0];
        float4 rb = redv4[1];
        float w, m0, m1;
        asm("v_max3_f32 %0, %1, %2, %3" : "=v"(m0) : "v"(ra.x), "v"(ra.y), "v"(ra.z));
        asm("v_max3_f32 %0, %1, %2, %3" : "=v"(m1) : "v"(ra.w), "v"(rb.x), "v"(rb.y));
        asm("v_max3_f32 %0, %1, %2, %3" : "=v"(m0) : "v"(m0), "v"(rb.z), "v"(rb.w));
        w = fmaxf(m0, m1);

        if (bmax == w) {   // rare: this thread holds a global-max value
            unsigned p = 0; float sx = 0.f, sy = 0.f, sz = 0.f, sw = 0.f;
            // descending scan, static indices; final assignment = smallest slot (min p)
#pragma unroll
            for (int j = NPAIR - 1; j >= 0; j--) {
                if (pd[2 * j + 1] == w) {
                    p = (2 * j + 1) * TPB + tid;
                    sx = px2[j].y; sy = py2[j].y; sz = pz2[j].y; sw = pw2[j].y;
                }
                if (pd[2 * j] == w) {
                    p = (2 * j) * TPB + tid;
                    sx = px2[j].x; sy = py2[j].x; sz = pz2[j].x; sw = pw2[j].x;
                }
            }
            u64 hp = (u64)p << 32;
            atomicMin(&slots[cur ^ 1][0], hp | (unsigned)__float_as_int(sx));
            atomicMin(&slots[cur ^ 1][1], hp | (unsigned)__float_as_int(sy));
            atomicMin(&slots[cur ^ 1][2], hp | (unsigned)__float_as_int(sz));
            atomicMin(&slots[cur ^ 1][3], hp | (unsigned)__float_as_int(sw));
        }
        __syncthreads();   // barrier B: winner slots final
        cur ^= 1;
    }
}

// ---------------- kernel 3b: FPS slow path (cnt > CAP; global arrays) ----------------
__global__ __launch_bounds__(1024) void k_fps_slow(const float* __restrict__ pc,
                                                   const unsigned char* __restrict__ mask,
                                                   const int* __restrict__ cnt,
                                                   float* __restrict__ dist,
                                                   int* __restrict__ idxsel) {
    int b = blockIdx.x, tid = threadIdx.x;
    int lane = tid & 63, wv = tid >> 6;
    if (cnt[b] <= CAP) return;
    __shared__ float redv[16];
    __shared__ int   redp[16];
    __shared__ int   bc;
    int firstn = 0x7fffffff;
    for (int n = tid; n < NN; n += 1024) {
        bool m = mask[(size_t)b * NN + n] != 0;
        dist[(size_t)b * NN + n] = m ? __builtin_inff() : -__builtin_inff();
        if (m && firstn == 0x7fffffff) firstn = n;
    }
    for (int off = 32; off >= 1; off >>= 1) {
        int on = __shfl_xor(firstn, off, 64);
        if (on < firstn) firstn = on;
    }
    if (lane == 0) redp[wv] = firstn;
    __syncthreads();
    if (tid < 64) {
        int p2 = (lane < 16) ? redp[lane] : 0x7fffffff;
        for (int off = 8; off >= 1; off >>= 1) {
            int op = __shfl_xor(p2, off, 64);
            if (op < p2) p2 = op;
        }
        if (lane == 0) bc = p2;
    }
    __threadfence_block();
    __syncthreads();
    int last = bc;
    for (int it = 0; it < MM; it++) {
        float cx = pc[((size_t)b * NN + last) * 3 + 0];
        float cy = pc[((size_t)b * NN + last) * 3 + 1];
        float cz = pc[((size_t)b * NN + last) * 3 + 2];
        float bv = -__builtin_inff();
        int bp = 0x7fffffff;
        for (int n = tid; n < NN; n += 1024) {
            float x = pc[((size_t)b * NN + n) * 3 + 0];
            float y = pc[((size_t)b * NN + n) * 3 + 1];
            float z = pc[((size_t)b * NN + n) * 3 + 2];
            float dx = __fsub_rn(x, cx), dy = __fsub_rn(y, cy), dz = __fsub_rn(z, cz);
            float d = __fadd_rn(__fadd_rn(__fmul_rn(dx, dx), __fmul_rn(dy, dy)),
                                __fmul_rn(dz, dz));
            float od = dist[(size_t)b * NN + n];
            float nd = fminf(od, d);
            dist[(size_t)b * NN + n] = nd;
            if (nd > bv) { bv = nd; bp = n; }
        }
        for (int off = 32; off >= 1; off >>= 1) {
            float ov = __shfl_xor(bv, off, 64);
            int   op = __shfl_xor(bp, off, 64);
            if (ov > bv || (ov == bv && op < bp)) { bv = ov; bp = op; }
        }
        if (lane == 0) { redv[wv] = bv; redp[wv] = bp; }
        if (tid == 1023) idxsel[b * MM + it] = last;
        __threadfence_block();
        __syncthreads();
        if (tid < 64) {
            float v2 = (lane < 16) ? redv[lane] : -__builtin_inff();
            int   p2 = (lane < 16) ? redp[lane] : 0x7fffffff;
            for (int off = 8; off >= 1; off >>= 1) {
                float ov = __shfl_xor(v2, off, 64);
                int   op = __shfl_xor(p2, off, 64);
                if (ov > v2 || (ov == v2 && op < p2)) { v2 = ov; p2 = op; }
            }
            if (lane == 0) bc = p2;
        }
        __threadfence_block();
        __syncthreads();
        last = bc;
    }
}

// ---------------- kernel 4: gather + pack [B, 516, 512] ----------------
__global__ __launch_bounds__(256) void k_gather(const float* __restrict__ pc,
                                                const float* __restrict__ feat,
                                                const float* __restrict__ g,
                                                const int* __restrict__ idxsel,
                                                float* __restrict__ out) {
    int bc_ = blockIdx.x;
    int b = bc_ / 516;
    int ch = bc_ % 516;
    for (int m = threadIdx.x; m < MM; m += 256) {
        int n = idxsel[b * MM + m];
        float v;
        if (ch < 512) v = feat[((size_t)b * CC + ch) * NN + n];
        else if (ch < 515) v = pc[((size_t)b * NN + n) * 3 + (ch - 512)];
        else v = g[b * NN + n];
        out[((size_t)b * 516 + ch) * MM + m] = v;
    }
}

extern "C" void kernel_launch(void* const* d_in, const int* in_sizes, int n_in,
                              void* d_out, int out_size, void* d_ws, size_t ws_size,
                              hipStream_t stream) {
    const float* pc    = (const float*)d_in[0];  // [B,N,3]
    const float* feat  = (const float*)d_in[1];  // [B,C,N]
    const float* Wobj  = (const float*)d_in[2];  // [2,C]
    const float* bobj  = (const float*)d_in[3];  // [2]
    const float* Wg    = (const float*)d_in[4];  // [C]
    const float* bg    = (const float*)d_in[5];  // [1]
    float* out = (float*)d_out;

    char* ws = (char*)d_ws;
    float*         g_buf   = (float*)(ws + OFF_G);
    unsigned char* mask    = (unsigned char*)(ws + OFF_MASK);
    int*           cnt     = (int*)(ws + OFF_CNT);
    int*           cidx    = (int*)(ws + OFF_CIDX);
    float4*        cxyzd   = (float4*)(ws + OFF_CXYZD);
    int*           idxsel  = (int*)(ws + OFF_IDXSEL);
    float*         dslow   = (float*)(ws + OFF_DSLOW);

    k_score<<<dim3(NN / 1024, BB), 256, 0, stream>>>(feat, Wobj, bobj, Wg, bg, g_buf, mask);
    k_compact<<<BB, 1024, 0, stream>>>(pc, mask, cnt, cidx, cxyzd);
    k_fps<<<BB, TPB, 0, stream>>>(cnt, cxyzd, idxsel);
    k_fps_slow<<<BB, 1024, 0, stream>>>(pc, mask, cnt, dslow, idxsel);
    k_gather<<<BB * 516, 256, 0, stream>>>(pc, feat, g_buf, idxsel, out);
}

// Round 8
// 675.610 us; speedup vs baseline: 1.1206x; 1.1206x over previous
//
#include <hip/hip_runtime.h>
#include <math.h>

#define BB 4
#define NN 32768
#define CC 512
#define MM 512
#define CAP 8192
#define TPB 512
#define KPT (CAP / TPB)    // 16 slots per thread
#define NPAIR (KPT / 2)

typedef float f32x2 __attribute__((ext_vector_type(2)));
typedef unsigned long long u64;

// ---- workspace layout (bytes) ----
#define OFF_G      0
#define OFF_MASK   (OFF_G + BB*NN*4)           // graspness f32
#define OFF_CNT    (OFF_MASK + BB*NN)          // mask u8
#define OFF_CIDX   (OFF_CNT + 256)             // cnt ints (padded)
#define OFF_CXYZD  (OFF_CIDX + BB*CAP*4)       // compacted orig indices
#define OFF_IDXSEL (OFF_CXYZD + BB*CAP*16)     // compacted float4 {x,y,z, idx_bits}
#define OFF_DSLOW  (OFF_IDXSEL + BB*MM*4)      // slow-path dist array
// total = OFF_DSLOW + BB*NN*4 ~= 1.85 MB

// ---------------- kernel 1: scoring heads + mask (scalar, 512 blocks) ----------------
__global__ __launch_bounds__(256) void k_score(const float* __restrict__ feat,
                                               const float* __restrict__ Wobj,
                                               const float* __restrict__ bobj,
                                               const float* __restrict__ Wg,
                                               const float* __restrict__ bg,
                                               float* __restrict__ g_out,
                                               unsigned char* __restrict__ mask_out) {
    __shared__ float w0[CC], w1[CC], wg[CC];
    for (int c = threadIdx.x; c < CC; c += 256) {
        w0[c] = Wobj[c];
        w1[c] = Wobj[CC + c];
        wg[c] = Wg[c];
    }
    __syncthreads();
    int b = blockIdx.y;
    int n = blockIdx.x * 256 + threadIdx.x;
    const float* f = feat + (size_t)b * CC * NN + n;
    double a0 = 0.0, a1 = 0.0, ag = 0.0;
#pragma unroll 8
    for (int c = 0; c < CC; c++) {
        double fv = (double)f[(size_t)c * NN];
        a0 += fv * (double)w0[c];
        a1 += fv * (double)w1[c];
        ag += fv * (double)wg[c];
    }
    float o0 = (float)(a0 + (double)bobj[0]);
    float o1 = (float)(a1 + (double)bobj[1]);
    float g  = (float)(ag + (double)bg[0]);
    g_out[b * NN + n] = g;
    // argmax([o0,o1])==1 requires strict o1>o0 (argmax picks first max)
    mask_out[b * NN + n] = (o1 > o0 && g > 0.1f) ? 1 : 0;
}

// ---------------- kernel 2: stable compaction of masked points ----------------
__global__ __launch_bounds__(1024) void k_compact(const float* __restrict__ pc,
                                                  const unsigned char* __restrict__ mask,
                                                  int* __restrict__ cnt,
                                                  int* __restrict__ cidx,
                                                  float4* __restrict__ cxyzd) {
    int b = blockIdx.x, tid = threadIdx.x;
    int lane = tid & 63, wv = tid >> 6;
    __shared__ int wcnt[16], woff[16];
    __shared__ int base;
    if (tid == 0) base = 0;
    __syncthreads();
    for (int ch = 0; ch < NN / 1024; ch++) {
        int n = ch * 1024 + tid;
        bool m = mask[(size_t)b * NN + n] != 0;
        unsigned long long bal = __ballot(m);
        int before = __popcll(bal & ((1ull << lane) - 1ull));
        if (lane == 0) wcnt[wv] = __popcll(bal);
        __syncthreads();
        if (tid == 0) {
            int r = base;
            for (int w = 0; w < 16; w++) { woff[w] = r; r += wcnt[w]; }
            base = r;
        }
        __syncthreads();
        if (m) {
            int pos = woff[wv] + before;
            if (pos < CAP) {
                cidx[b * CAP + pos] = n;
                const float* p = pc + ((size_t)b * NN + n) * 3;
                cxyzd[b * CAP + pos] = make_float4(p[0], p[1], p[2], __int_as_float(n));
            }
        }
        __syncthreads();
    }
    if (tid == 0) cnt[b] = base;
}

// ---- DPP reduce steps (builtin form: compiler handles VALU->DPP hazard nops) ----
template<int CTRL, int RMASK>
__device__ __forceinline__ float dpp_fmax(float v) {
    int o = __builtin_amdgcn_update_dpp(__float_as_int(v), __float_as_int(v),
                                        CTRL, RMASK, 0xF, false);
    return fmaxf(v, __int_as_float(o));
}
template<int CTRL, int RMASK>
__device__ __forceinline__ unsigned dpp_umax(unsigned v) {
    unsigned o = (unsigned)__builtin_amdgcn_update_dpp((int)v, (int)v,
                                                       CTRL, RMASK, 0xF, false);
    return (o > v) ? o : v;
}

// ---------------- kernel 3: FPS — value-first inner loop, single barrier/iter ----------
__global__ __launch_bounds__(TPB, 1) void k_fps(const int* __restrict__ cnt,
                                                const float4* __restrict__ cxyzd_g,
                                                int* __restrict__ idxsel) {
    int b = blockIdx.x, tid = threadIdx.x;
    int nc = cnt[b];
    if (nc == 0) {  // no graspable points: reference selects index 0 forever
        for (int i = tid; i < MM; i += TPB) idxsel[b * MM + i] = 0;
        return;
    }
    if (nc > CAP) return;  // slow-path kernel handles this

    __shared__ float4 xyzc[CAP];      // 128 KiB: {x,y,z, orig_idx_bits}, read-only in loop
    __shared__ u64 sred[3];           // rotating argmax key {val_bits<<32 | ~p}

    f32x2 px2[NPAIR], py2[NPAIR], pz2[NPAIR];
    float pd[KPT];
    const float4* src = cxyzd_g + (size_t)b * CAP;
#pragma unroll
    for (int j = 0; j < NPAIR; j++) {
        int p0 = (2 * j) * TPB + tid;
        int p1 = (2 * j + 1) * TPB + tid;
        bool v0 = p0 < nc, v1 = p1 < nc;
        float4 a = v0 ? src[p0] : make_float4(0.f, 0.f, 0.f, 0.f);
        float4 c = v1 ? src[p1] : make_float4(0.f, 0.f, 0.f, 0.f);
        px2[j] = (f32x2){a.x, c.x};
        py2[j] = (f32x2){a.y, c.y};
        pz2[j] = (f32x2){a.z, c.z};
        pd[2 * j]     = v0 ? __builtin_inff() : -__builtin_inff();
        pd[2 * j + 1] = v1 ? __builtin_inff() : -__builtin_inff();
        if (v0) xyzc[p0] = a;
        if (v1) xyzc[p1] = c;
    }
    if (tid == 0) { sred[0] = 0ull; sred[1] = 0ull; sred[2] = 0ull; }
    __syncthreads();

    int last = 0;   // compacted index of first masked point
    int s = 0;      // rotating slot
    for (int it = 0; it < MM; it++) {
        float4 c4 = xyzc[last];   // broadcast LDS read; .w = original index bits
        if (tid == 0) {
            idxsel[b * MM + it] = __float_as_int(c4.w);
            int zs = (s == 2) ? 0 : s + 1;   // zero next slot (its readers synced 1 barrier ago)
            sred[zs] = 0ull;
        }
        f32x2 ncx = {-c4.x, -c4.x};
        f32x2 ncy = {-c4.y, -c4.y};
        f32x2 ncz = {-c4.z, -c4.z};

        float bmax = -__builtin_inff();
#pragma unroll
        for (int j = 0; j < NPAIR; j++) {
            f32x2 d2, t;
            // exact f32 per half, no contraction: ((dx*dx + dy*dy) + dz*dz)
            asm("v_pk_add_f32 %0, %2, %4\n\t"
                "v_pk_add_f32 %1, %3, %5\n\t"
                "v_pk_mul_f32 %0, %0, %0\n\t"
                "v_pk_mul_f32 %1, %1, %1\n\t"
                "v_pk_add_f32 %0, %0, %1\n\t"
                "v_pk_add_f32 %1, %6, %7\n\t"
                "v_pk_mul_f32 %1, %1, %1\n\t"
                "v_pk_add_f32 %0, %0, %1"
                : "=&v"(d2), "=&v"(t)
                : "v"(px2[j]), "v"(py2[j]), "v"(ncx), "v"(ncy), "v"(pz2[j]), "v"(ncz));
            float nd0 = fminf(pd[2 * j], d2.x);
            float nd1 = fminf(pd[2 * j + 1], d2.y);
            pd[2 * j] = nd0;
            pd[2 * j + 1] = nd1;
            // running max via single v_max3 (exact; value domain has no NaN/-0)
            asm("v_max3_f32 %0, %1, %2, %3" : "=v"(bmax) : "v"(nd0), "v"(nd1), "v"(bmax));
        }

        // wave value max (lane 63 ends with it), clamped to >=0 so empty waves are inert
        float wmax = bmax;
        wmax = dpp_fmax<0x111, 0xF>(wmax);  // row_shr:1
        wmax = dpp_fmax<0x112, 0xF>(wmax);  // row_shr:2
        wmax = dpp_fmax<0x114, 0xF>(wmax);  // row_shr:4
        wmax = dpp_fmax<0x118, 0xF>(wmax);  // row_shr:8
        wmax = dpp_fmax<0x142, 0xA>(wmax);  // row_bcast:15 -> rows 1,3
        wmax = dpp_fmax<0x143, 0xC>(wmax);  // row_bcast:31 -> rows 2,3
        wmax = fmaxf(wmax, 0.0f);
        // broadcast wave max to all lanes (SGPR)
        float wvmax = __int_as_float(__builtin_amdgcn_readlane(__float_as_int(wmax), 63));

        // rare winner lanes: find min compacted idx among own slots == wvmax
        unsigned nbp = 0u;
        if (bmax == wvmax) {
            unsigned p = 0;
            // descending scan, static indices; final assignment = smallest p
#pragma unroll
            for (int j = NPAIR - 1; j >= 0; j--) {
                if (pd[2 * j + 1] == wvmax) p = (2 * j + 1) * TPB + tid;
                if (pd[2 * j] == wvmax)     p = (2 * j) * TPB + tid;
            }
            nbp = ~p;
        }
        // wave max of ~p -> min p among winners (0 for non-winners never wins)
        nbp = dpp_umax<0x111, 0xF>(nbp);
        nbp = dpp_umax<0x112, 0xF>(nbp);
        nbp = dpp_umax<0x114, 0xF>(nbp);
        nbp = dpp_umax<0x118, 0xF>(nbp);
        nbp = dpp_umax<0x142, 0xA>(nbp);
        nbp = dpp_umax<0x143, 0xC>(nbp);

        if ((tid & 63) == 63) {
            u64 key = ((u64)(unsigned)__float_as_int(wvmax) << 32) | nbp;
            atomicMax(&sred[s], key);
        }
        __syncthreads();   // single barrier: all wave keys published

        u64 w = sred[s];
        last = (int)(~(unsigned)w);
        s = (s == 2) ? 0 : s + 1;
    }
}

// ---------------- kernel 3b: FPS slow path (cnt > CAP; global arrays) ----------------
__global__ __launch_bounds__(1024) void k_fps_slow(const float* __restrict__ pc,
                                                   const unsigned char* __restrict__ mask,
                                                   const int* __restrict__ cnt,
                                                   float* __restrict__ dist,
                                                   int* __restrict__ idxsel) {
    int b = blockIdx.x, tid = threadIdx.x;
    int lane = tid & 63, wv = tid >> 6;
    if (cnt[b] <= CAP) return;
    __shared__ float redv[16];
    __shared__ int   redp[16];
    __shared__ int   bc;
    int firstn = 0x7fffffff;
    for (int n = tid; n < NN; n += 1024) {
        bool m = mask[(size_t)b * NN + n] != 0;
        dist[(size_t)b * NN + n] = m ? __builtin_inff() : -__builtin_inff();
        if (m && firstn == 0x7fffffff) firstn = n;
    }
    for (int off = 32; off >= 1; off >>= 1) {
        int on = __shfl_xor(firstn, off, 64);
        if (on < firstn) firstn = on;
    }
    if (lane == 0) redp[wv] = firstn;
    __syncthreads();
    if (tid < 64) {
        int p2 = (lane < 16) ? redp[lane] : 0x7fffffff;
        for (int off = 8; off >= 1; off >>= 1) {
            int op = __shfl_xor(p2, off, 64);
            if (op < p2) p2 = op;
        }
        if (lane == 0) bc = p2;
    }
    __threadfence_block();
    __syncthreads();
    int last = bc;
    for (int it = 0; it < MM; it++) {
        float cx = pc[((size_t)b * NN + last) * 3 + 0];
        float cy = pc[((size_t)b * NN + last) * 3 + 1];
        float cz = pc[((size_t)b * NN + last) * 3 + 2];
        float bv = -__builtin_inff();
        int bp = 0x7fffffff;
        for (int n = tid; n < NN; n += 1024) {
            float x = pc[((size_t)b * NN + n) * 3 + 0];
            float y = pc[((size_t)b * NN + n) * 3 + 1];
            float z = pc[((size_t)b * NN + n) * 3 + 2];
            float dx = __fsub_rn(x, cx), dy = __fsub_rn(y, cy), dz = __fsub_rn(z, cz);
            float d = __fadd_rn(__fadd_rn(__fmul_rn(dx, dx), __fmul_rn(dy, dy)),
                                __fmul_rn(dz, dz));
            float od = dist[(size_t)b * NN + n];
            float nd = fminf(od, d);
            dist[(size_t)b * NN + n] = nd;
            if (nd > bv) { bv = nd; bp = n; }
        }
        for (int off = 32; off >= 1; off >>= 1) {
            float ov = __shfl_xor(bv, off, 64);
            int   op = __shfl_xor(bp, off, 64);
            if (ov > bv || (ov == bv && op < bp)) { bv = ov; bp = op; }
        }
        if (lane == 0) { redv[wv] = bv; redp[wv] = bp; }
        if (tid == 1023) idxsel[b * MM + it] = last;
        __threadfence_block();
        __syncthreads();
        if (tid < 64) {
            float v2 = (lane < 16) ? redv[lane] : -__builtin_inff();
            int   p2 = (lane < 16) ? redp[lane] : 0x7fffffff;
            for (int off = 8; off >= 1; off >>= 1) {
                float ov = __shfl_xor(v2, off, 64);
                int   op = __shfl_xor(p2, off, 64);
                if (ov > v2 || (ov == v2 && op < p2)) { v2 = ov; p2 = op; }
            }
            if (lane == 0) bc = p2;
        }
        __threadfence_block();
        __syncthreads();
        last = bc;
    }
}

// ---------------- kernel 4: gather + pack [B, 516, 512] ----------------
__global__ __launch_bounds__(256) void k_gather(const float* __restrict__ pc,
                                                const float* __restrict__ feat,
                                                const float* __restrict__ g,
                                                const int* __restrict__ idxsel,
                                                float* __restrict__ out) {
    int bc_ = blockIdx.x;
    int b = bc_ / 516;
    int ch = bc_ % 516;
    for (int m = threadIdx.x; m < MM; m += 256) {
        int n = idxsel[b * MM + m];
        float v;
        if (ch < 512) v = feat[((size_t)b * CC + ch) * NN + n];
        else if (ch < 515) v = pc[((size_t)b * NN + n) * 3 + (ch - 512)];
        else v = g[b * NN + n];
        out[((size_t)b * 516 + ch) * MM + m] = v;
    }
}

extern "C" void kernel_launch(void* const* d_in, const int* in_sizes, int n_in,
                              void* d_out, int out_size, void* d_ws, size_t ws_size,
                              hipStream_t stream) {
    const float* pc    = (const float*)d_in[0];  // [B,N,3]
    const float* feat  = (const float*)d_in[1];  // [B,C,N]
    const float* Wobj  = (const float*)d_in[2];  // [2,C]
    const float* bobj  = (const float*)d_in[3];  // [2]
    const float* Wg    = (const float*)d_in[4];  // [C]
    const float* bg    = (const float*)d_in[5];  // [1]
    float* out = (float*)d_out;

    char* ws = (char*)d_ws;
    float*         g_buf   = (float*)(ws + OFF_G);
    unsigned char* mask    = (unsigned char*)(ws + OFF_MASK);
    int*           cnt     = (int*)(ws + OFF_CNT);
    int*           cidx    = (int*)(ws + OFF_CIDX);
    float4*        cxyzd   = (float4*)(ws + OFF_CXYZD);
    int*           idxsel  = (int*)(ws + OFF_IDXSEL);
    float*         dslow   = (float*)(ws + OFF_DSLOW);

    k_score<<<dim3(NN / 256, BB), 256, 0, stream>>>(feat, Wobj, bobj, Wg, bg, g_buf, mask);
    k_compact<<<BB, 1024, 0, stream>>>(pc, mask, cnt, cidx, cxyzd);
    k_fps<<<BB, TPB, 0, stream>>>(cnt, cxyzd, idxsel);
    k_fps_slow<<<BB, 1024, 0, stream>>>(pc, mask, cnt, dslow, idxsel);
    k_gather<<<BB * 516, 256, 0, stream>>>(pc, feat, g_buf, idxsel, out);
}